// Round 5
// baseline (74.881 us; speedup 1.0000x reference)
//
#include <hip/hip_runtime.h>

// Problem constants (match reference)
#define B_  8
#define L_  512
#define C_  6
#define N_  (B_ * L_)
#define K_  9
#define BIGF 1e10f

// Output layout (flat float32, concatenated in return order)
#define NK        (N_ * K_)               // 36864
#define OFF_DKNN  0
#define OFF_SRC   (NK)
#define OFF_DST   (2 * NK)
#define OFF_VALID (3 * NK)
#define OFF_GLB   (4 * NK)
#define GLB_PER   (2 * L_ - 1)            // 1023
#define GLB_TOT   (2 * B_ * GLB_PER)      // 16368
#define OFF_SEQ   (OFF_GLB + GLB_TOT)
#define SEQ_PER   (2 * (L_ - 2))          // 1020
#define SEQ_TOT   (2 * B_ * SEQ_PER)      // 16320

#define TPB 512            // 8 waves; wave w owns cols {w*64+lane}; selects row w
#define RPB 8              // rows per block

typedef float v2f __attribute__((ext_vector_type(2)));

static __device__ __forceinline__ unsigned umin32(unsigned a, unsigned b) {
    return a < b ? a : b;
}

// Flipped structure: columns live in REGISTERS (one per lane, -2 pre-folded),
// rows are wave-uniform scalar loads. Each lane computes its column against
// the block's 8 rows and writes 32-bit quantized keys (23-bit d2 | 9-bit col)
// to kbuf; after one barrier, wave w runs the 9-round in-wave argmin on row w.
// Distance phase does ZERO LDS reads (vs 48 ds_read_b128/wave before).
__global__ __launch_bounds__(TPB, 4) void fused_kernel(const float* __restrict__ X,
                                                       const int* __restrict__ AP,
                                                       const int* __restrict__ S,
                                                       const int* __restrict__ sec,
                                                       float* __restrict__ out) {
    __shared__ unsigned kbuf[RPB][L_];   // 16 KB

    const int tid = threadIdx.x;
    const int lane = tid & 63;
    const int wv = tid >> 6;
    const int row0 = blockIdx.x * RPB;
    const int gbase = row0 & ~(L_ - 1);      // graph start (8 | 512, so uniform)
    const int mycol = (wv << 6) | lane;      // this lane's column, 0..511

    // ---- static glb/seq edge lists (first 32 blocks' threads) ----
    {
        const int gt = blockIdx.x * TPB + tid;
        if (gt < GLB_TOT) {
            const int r = gt / (B_ * GLB_PER);
            const int rem = gt % (B_ * GLB_PER);
            const int b = rem / GLB_PER;
            const int q = rem % GLB_PER;
            int v;
            if (r == 0) v = (q < L_) ? 0 : (q - (L_ - 1));   // src: [0]*L ++ [1..L-1]
            else        v = (q < L_) ? q : 0;                // dst: [0..L-1] ++ [0]*(L-1)
            out[OFF_GLB + gt] = (float)(v + b * L_);
        }
        if (gt < SEQ_TOT) {
            const int r = gt / (B_ * SEQ_PER);
            const int rem = gt % (B_ * SEQ_PER);
            const int b = rem / SEQ_PER;
            const int q = rem % SEQ_PER;
            int v;
            if (r == 0) v = (q < L_ - 2) ? (q + 1) : (q - (L_ - 2) + 2);  // [1..510]++[2..511]
            else        v = (q < L_ - 2) ? (q + 2) : (q - (L_ - 2) + 1);  // [2..511]++[1..510]
            out[OFF_SEQ + gt] = (float)(v + b * L_);
        }
    }

    // ---- load own column into registers, fold -2 into coords, masks into sq ----
    v2f cmx[3], cmy[3], cmz[3], csq[3];
    {
        const int cnode = gbase + mycol;
        const float* xc = X + (size_t)cnode * 18;
        float cx[C_], cy[C_], cz[C_];
        // 72 B record is 8-aligned: load as 9x float2
        float2 h[9];
#pragma unroll
        for (int i = 0; i < 9; ++i) h[i] = ((const float2*)xc)[i];
        const float* hf = (const float*)h;
#pragma unroll
        for (int c = 0; c < C_; ++c) {
            cx[c] = hf[c * 3]; cy[c] = hf[c * 3 + 1]; cz[c] = hf[c * 3 + 2];
        }
        const float bias_g = (S[cnode] == 0) ? BIGF : 0.0f;
        float cq[C_];
#pragma unroll
        for (int c = 0; c < C_; ++c) {
            float sq = (cx[c] * cx[c] + cy[c] * cy[c]) + cz[c] * cz[c];
            if (AP[cnode * C_ + c] == 0) sq += BIGF;   // padded channel loses every min
            cq[c] = sq + bias_g;                        // global node loses every min
        }
#pragma unroll
        for (int p = 0; p < 3; ++p) {
            cmx[p] = (v2f){-2.0f * cx[2 * p], -2.0f * cx[2 * p + 1]};
            cmy[p] = (v2f){-2.0f * cy[2 * p], -2.0f * cy[2 * p + 1]};
            cmz[p] = (v2f){-2.0f * cz[2 * p], -2.0f * cz[2 * p + 1]};
            csq[p] = (v2f){cq[2 * p], cq[2 * p + 1]};
        }
    }

    // ---- 8 rows: wave-uniform row record vs in-register column ----
#pragma unroll
    for (int r = 0; r < RPB; ++r) {
        const int rnode = row0 + r;                    // uniform across the block
        const float* xr = X + (size_t)rnode * 18;
        const float rbias = (S[rnode] == 0) ? BIGF : 0.0f;
        float rx[C_], ry[C_], rz[C_], rq[C_];
#pragma unroll
        for (int c = 0; c < C_; ++c) {
            rx[c] = xr[c * 3]; ry[c] = xr[c * 3 + 1]; rz[c] = xr[c * 3 + 2];
            float sq = (rx[c] * rx[c] + ry[c] * ry[c]) + rz[c] * rz[c];
            if (AP[rnode * C_ + c] == 0) sq += BIGF;
            rq[c] = sq + rbias;
        }
        v2f md[3] = {(v2f)(3.0e38f), (v2f)(3.0e38f), (v2f)(3.0e38f)};
#pragma unroll
        for (int c = 0; c < C_; ++c) {
            const v2f seed = (v2f){rq[c], rq[c]};
            const v2f sx = (v2f){rx[c], rx[c]};
            const v2f sy = (v2f){ry[c], ry[c]};
            const v2f sz = (v2f){rz[c], rz[c]};
#pragma unroll
            for (int p = 0; p < 3; ++p) {
                v2f t = __builtin_elementwise_fma(sx, cmx[p], seed);
                t = __builtin_elementwise_fma(sy, cmy[p], t);
                t = __builtin_elementwise_fma(sz, cmz[p], t);
                md[p] = __builtin_elementwise_min(md[p], t);
            }
        }
        float m = 3.0e38f;
#pragma unroll
        for (int p = 0; p < 3; ++p) {
            const v2f ms = md[p] + csq[p];
            m = fminf(m, fminf(ms.x, ms.y));
        }
        m = fmaxf(m, 0.0f);   // d2; masked pairs land >= ~1e10
        kbuf[r][mycol] = (__float_as_uint(m) & 0xFFFFFE00u) | (unsigned)mycol;
    }
    __syncthreads();

    // ---- wave w: 9 rounds of stable argmin on row w's 512 keys ----
    unsigned v[8];
#pragma unroll
    for (int s = 0; s < 8; ++s) v[s] = kbuf[wv][s * 64 + lane];

    unsigned mine = 0xFFFFFFFFu;
#pragma unroll
    for (int t = 0; t < K_; ++t) {
        unsigned loc = v[0];
#pragma unroll
        for (int s = 1; s < 8; ++s) loc = umin32(loc, v[s]);
#pragma unroll
        for (int off = 32; off >= 1; off >>= 1) {
            const unsigned o = (unsigned)__shfl_xor((int)loc, off, 64);
            loc = umin32(loc, o);
        }
        if (lane == t) mine = loc;                 // lane t keeps round-t winner
#pragma unroll
        for (int s = 0; s < 8; ++s)                // remove winner (keys unique)
            v[s] = (v[s] == loc) ? 0xFFFFFFFFu : v[s];
    }

    // ---- epilogue: lanes 0..8 write the 4 per-edge outputs for row (row0+wv) ----
    if (lane < K_) {
        const int row = row0 + wv;
        const int col = (int)(mine & 511u);
        const float d2 = __uint_as_float(mine & 0xFFFFFE00u);
        const bool masked = (d2 >= 1.0e9f);        // valid pairs are < ~1e5
        const float dval = masked ? BIGF : sqrtf(d2);
        const int dst = gbase + col;
        const bool valid = !masked && (sec[row] == sec[dst]);
        const size_t o = (size_t)row * K_ + lane;
        out[OFF_DKNN + o]  = dval;
        out[OFF_SRC + o]   = (float)row;
        out[OFF_DST + o]   = valid ? (float)dst : -1.0f;
        out[OFF_VALID + o] = valid ? 1.0f : 0.0f;
    }
}

extern "C" void kernel_launch(void* const* d_in, const int* in_sizes, int n_in,
                              void* d_out, int out_size, void* d_ws, size_t ws_size,
                              hipStream_t stream) {
    (void)in_sizes; (void)n_in; (void)out_size; (void)d_ws; (void)ws_size;
    const float* X   = (const float*)d_in[0];
    const int*   AP  = (const int*)d_in[1];
    const int*   S   = (const int*)d_in[2];
    const int*   sec = (const int*)d_in[3];
    float* out = (float*)d_out;

    hipLaunchKernelGGL(fused_kernel, dim3(N_ / RPB), dim3(TPB), 0, stream,
                       X, AP, S, sec, out);
}